// Round 19
// baseline (179.740 us; speedup 1.0000x reference)
//
#include <hip/hip_runtime.h>
#include <math.h>

constexpr int E = 4;
constexpr int D = 32;
constexpr int K = 16;
constexpr int H = 32;

typedef float f32x4 __attribute__((ext_vector_type(4)));

// f32 -> nearest bf16-representable f32 (RNE, matches jax/ml_dtypes cast)
__device__ __forceinline__ float bf16r(float f) {
    unsigned int u = __float_as_uint(f);
    u = (u + 0x7FFFu + ((u >> 16) & 1u)) & 0xFFFF0000u;
    return __uint_as_float(u);
}

// ---- prep: bf16-round all weight arrays into d_ws (flat f32) -------------
__global__ void mote_prep(const float* __restrict__ r1, const float* __restrict__ b1,
                          const float* __restrict__ r2, const float* __restrict__ b2,
                          const float* __restrict__ f,  const float* __restrict__ sp,
                          const float* __restrict__ rk, const float* __restrict__ wv,
                          float* __restrict__ ws)
{
    int t = blockIdx.x * blockDim.x + threadIdx.x;
    float v;
    if      (t <   32) v = r1[t];
    else if (t <   64) v = b1[t - 32];
    else if (t <  192) v = r2[t - 64];
    else if (t <  196) v = b2[t - 192];
    else if (t < 1220) v = f [t - 196];
    else if (t < 1732) v = sp[t - 1220];
    else if (t < 2244) v = rk[t - 1732];
    else if (t < 2756) v = wv[t - 2244];
    else return;
    ws[t] = bf16r(v);
}

constexpr int LROW = 36;   // 32 payload + 4 pad f32

// ---- main: r17 structure (f32 router + rare f64 fallback, wave-private
//      f32 LDS transpose, zero barriers, nt stores, sincos recurrence,
//      __expf) + WAVE-ROTATED expert order: wave w processes experts in
//      order (w, w+1, w+2, w+3) mod 4. Wave-uniform switch (no divergence
//      within a wave). Breaks cross-wave store-phase lockstep so the write
//      pipe drains continuously under other waves' compute. Per-expert
//      numerics byte-identical to r17 (canary absmax 0.01751709).
__global__ __launch_bounds__(256) void mote_main(
    const float* __restrict__ x_in, int B,
    const float* __restrict__ ws,
    float* __restrict__ out_emb, float* __restrict__ out_rw,
    float* __restrict__ out_mask)
{
    __shared__ float sl[4][64][LROW];   // per-wave private slabs

    const int tid  = threadIdx.x;
    const int wid  = tid >> 6;
    const int lane = tid & 63;
    const size_t blockbase = (size_t)blockIdx.x * 256;
    const int b = (int)blockbase + tid;
    const bool valid = b < B;

    const float* rw1 = ws;
    const float* rb1 = ws + 32;
    const float* rw2 = ws + 64;
    const float* rb2 = ws + 192;
    const float* wf  = ws + 196;
    const float* wsp = ws + 1220;
    const float* wrk = ws + 1732;
    const float* wwv = ws + 2244;

    const float xb = bf16r(valid ? x_in[b] : 0.0f);

    // ---------------- router MLP in f32 + rare f64 fallback ----------------
    float lv[E] = { rb2[0], rb2[1], rb2[2], rb2[3] };
#pragma unroll
    for (int j = 0; j < H; ++j) {
        const float h = fmaxf(fmaf(xb, rw1[j], rb1[j]), 0.0f);
        lv[0] = fmaf(h, rw2[j * E + 0], lv[0]);
        lv[1] = fmaf(h, rw2[j * E + 1], lv[1]);
        lv[2] = fmaf(h, rw2[j * E + 2], lv[2]);
        lv[3] = fmaf(h, rw2[j * E + 3], lv[3]);
    }
    int i1 = 0;
#pragma unroll
    for (int e = 1; e < E; ++e) if (lv[e] > lv[i1]) i1 = e;
    int i2 = (i1 == 0) ? 1 : 0;
#pragma unroll
    for (int e = 0; e < E; ++e) if (e != i1 && lv[e] > lv[i2]) i2 = e;

    float third = -3.4e38f;
#pragma unroll
    for (int e = 0; e < E; ++e)
        if (e != i1 && e != i2) third = fmaxf(third, lv[e]);
    const bool close =
        (lv[i2] - third) < 1e-3f * fmaxf(1.0f, fabsf(lv[i2]));

    if (__any((int)close)) {
        const double xd = (double)xb;
        double l0 = (double)rb2[0], l1 = (double)rb2[1];
        double l2 = (double)rb2[2], l3 = (double)rb2[3];
#pragma unroll
        for (int j = 0; j < H; ++j) {
            const double h = fmax(fma(xd, (double)rw1[j], (double)rb1[j]), 0.0);
            l0 = fma(h, (double)rw2[j * E + 0], l0);
            l1 = fma(h, (double)rw2[j * E + 1], l1);
            l2 = fma(h, (double)rw2[j * E + 2], l2);
            l3 = fma(h, (double)rw2[j * E + 3], l3);
        }
        double ld[E] = { l0, l1, l2, l3 };
        i1 = 0;
#pragma unroll
        for (int e = 1; e < E; ++e) if (ld[e] > ld[i1]) i1 = e;
        i2 = (i1 == 0) ? 1 : 0;
#pragma unroll
        for (int e = 0; e < E; ++e) if (e != i1 && ld[e] > ld[i2]) i2 = e;
#pragma unroll
        for (int e = 0; e < E; ++e) lv[e] = (float)ld[e];
    }

    const float mx = fmaxf(fmaxf(lv[0], lv[1]), fmaxf(lv[2], lv[3]));
    const float e0 = __expf(lv[0] - mx);
    const float e1 = __expf(lv[1] - mx);
    const float e2 = __expf(lv[2] - mx);
    const float e3 = __expf(lv[3] - mx);
    const float inv = 1.0f / (e0 + e1 + e2 + e3);
    float w[E] = { e0 * inv, e1 * inv, e2 * inv, e3 * inv };

    float dw[E] = {0.f, 0.f, 0.f, 0.f};
    float mk[E] = {0.f, 0.f, 0.f, 0.f};
    dw[i1] = w[i1]; dw[i2] = w[i2];
    mk[i1] = 1.0f;  mk[i2] = 1.0f;

    if (valid) {
        f32x4 vrw = { bf16r(w[0]), bf16r(w[1]), bf16r(w[2]), bf16r(w[3]) };
        __builtin_nontemporal_store(vrw,
            reinterpret_cast<f32x4*>(out_rw + (size_t)E * b));
        f32x4 vmk = { mk[0], mk[1], mk[2], mk[3] };
        __builtin_nontemporal_store(vmk,
            reinterpret_cast<f32x4*>(out_mask + (size_t)E * b));
    }

    float acc[D];
    float (*slab)[LROW] = sl[wid];
    const size_t wrowbase = blockbase + (size_t)wid * 64;
    const int r8 = lane >> 3;
    const int q  = lane & 7;

    // stage + cooperative full-line nt store (identical to r17)
#define STAGE_STORE(EIDX, DWV)                                                  \
    do {                                                                        \
        _Pragma("unroll")                                                       \
        for (int c = 0; c < D / 4; ++c) {                                       \
            f32x4 pk = { bf16r(acc[4*c+0] * (DWV)), bf16r(acc[4*c+1] * (DWV)),  \
                         bf16r(acc[4*c+2] * (DWV)), bf16r(acc[4*c+3] * (DWV)) };\
            *reinterpret_cast<f32x4*>(&slab[lane][c * 4]) = pk;                 \
        }                                                                       \
        _Pragma("unroll")                                                       \
        for (int it = 0; it < 8; ++it) {                                        \
            const int row = it * 8 + r8;                                        \
            const f32x4 v =                                                     \
                *reinterpret_cast<const f32x4*>(&slab[row][q * 4]);             \
            if (wrowbase + row < (size_t)B)                                     \
                __builtin_nontemporal_store(v,                                  \
                    reinterpret_cast<f32x4*>(out_emb + (wrowbase + row) * (E * D) \
                                             + (EIDX) * D + q * 4));            \
        }                                                                       \
    } while (0)

    // Wave-rotated expert order: e = (s + wid) & 3. Switch is wave-uniform.
#pragma unroll
    for (int s = 0; s < 4; ++s) {
        const int e = (s + wid) & 3;
        switch (e) {
        case 0: {  // fourier — 1 sincosf + angle-addition recurrence
            float phi[2 * K];
            float s1, c1;
            sincosf(xb, &s1, &c1);
            phi[0] = s1; phi[K] = c1;
            float sk = s1, ck = c1;
#pragma unroll
            for (int k = 1; k < K; ++k) {
                const float sn = fmaf(sk, c1,  ck * s1);
                const float cn = fmaf(ck, c1, -sk * s1);
                sk = sn; ck = cn;
                phi[k]     = sk;
                phi[K + k] = ck;
            }
#pragma unroll
            for (int d = 0; d < D; ++d) acc[d] = 0.0f;
#pragma unroll
            for (int k = 0; k < 2 * K; ++k) {
                const float p = phi[k];
#pragma unroll
                for (int d = 0; d < D; ++d)
                    acc[d] = fmaf(p, wf[k * D + d], acc[d]);
            }
            STAGE_STORE(0, dw[0]);
            break;
        }
        case 1: {  // spline relu(x-knot)^3
            float phi[K];
#pragma unroll
            for (int k = 0; k < K; ++k) {
                const float knot = (float)(-2.0 + (double)k * (4.0 / 15.0));
                const float r = fmaxf(xb - knot, 0.0f);
                phi[k] = r * r * r;
            }
#pragma unroll
            for (int d = 0; d < D; ++d) acc[d] = 0.0f;
#pragma unroll
            for (int k = 0; k < K; ++k) {
                const float p = phi[k];
#pragma unroll
                for (int d = 0; d < D; ++d)
                    acc[d] = fmaf(p, wsp[k * D + d], acc[d]);
            }
            STAGE_STORE(1, dw[1]);
            break;
        }
        case 2: {  // rkhs gaussian exp(-4 t^2)
            float phi[K];
#pragma unroll
            for (int k = 0; k < K; ++k) {
                const float knot = (float)(-2.0 + (double)k * (4.0 / 15.0));
                const float t = xb - knot;
                phi[k] = __expf(-4.0f * t * t);
            }
#pragma unroll
            for (int d = 0; d < D; ++d) acc[d] = 0.0f;
#pragma unroll
            for (int k = 0; k < K; ++k) {
                const float p = phi[k];
#pragma unroll
                for (int d = 0; d < D; ++d)
                    acc[d] = fmaf(p, wrk[k * D + d], acc[d]);
            }
            STAGE_STORE(2, dw[2]);
            break;
        }
        default: {  // ricker wavelet (1-z^2) exp(-z^2/2), z = 2 (x - knot)
            float phi[K];
#pragma unroll
            for (int k = 0; k < K; ++k) {
                const float knot = (float)(-2.0 + (double)k * (4.0 / 15.0));
                const float z  = (xb - knot) * 2.0f;
                const float z2 = z * z;
                phi[k] = (1.0f - z2) * __expf(-0.5f * z2);
            }
#pragma unroll
            for (int d = 0; d < D; ++d) acc[d] = 0.0f;
#pragma unroll
            for (int k = 0; k < K; ++k) {
                const float p = phi[k];
#pragma unroll
                for (int d = 0; d < D; ++d)
                    acc[d] = fmaf(p, wwv[k * D + d], acc[d]);
            }
            STAGE_STORE(3, dw[3]);
            break;
        }
        }
    }
#undef STAGE_STORE
}

extern "C" void kernel_launch(void* const* d_in, const int* in_sizes, int n_in,
                              void* d_out, int out_size, void* d_ws, size_t ws_size,
                              hipStream_t stream)
{
    const int B = in_sizes[0];   // timestamp_input (B,1) f32
    const float* x   = (const float*)d_in[0];
    const float* rw1 = (const float*)d_in[1];
    const float* rb1 = (const float*)d_in[2];
    const float* rw2 = (const float*)d_in[3];
    const float* rb2 = (const float*)d_in[4];
    const float* wf  = (const float*)d_in[5];
    const float* wsp = (const float*)d_in[6];
    const float* wrk = (const float*)d_in[7];
    const float* wwv = (const float*)d_in[8];

    float* ws = (float*)d_ws;

    // tuple layout, flat f32 (bf16-grained values) in return order:
    //   final_embedding (B*128) | raw_weights (B*4) | mask (B*4 as 1.0/0.0)
    float* out      = (float*)d_out;
    float* out_emb  = out;
    float* out_rw   = out + (size_t)B * (E * D);
    float* out_mask = out_rw + (size_t)B * E;

    hipLaunchKernelGGL(mote_prep, dim3(11), dim3(256), 0, stream,
                       rw1, rb1, rw2, rb2, wf, wsp, wrk, wwv, ws);

    const int block = 256;
    const int grid  = (B + block - 1) / block;
    hipLaunchKernelGGL(mote_main, dim3(grid), dim3(block), 0, stream,
                       x, B, ws, out_emb, out_rw, out_mask);
}

// Round 20
// 68.540 us; speedup vs baseline: 2.6224x; 2.6224x over previous
//
#include <hip/hip_runtime.h>
#include <math.h>

constexpr int E = 4;
constexpr int D = 32;
constexpr int K = 16;
constexpr int H = 32;

typedef float f32x4 __attribute__((ext_vector_type(4)));

// f32 -> nearest bf16-representable f32 (RNE, matches jax/ml_dtypes cast)
__device__ __forceinline__ float bf16r(float f) {
    unsigned int u = __float_as_uint(f);
    u = (u + 0x7FFFu + ((u >> 16) & 1u)) & 0xFFFF0000u;
    return __uint_as_float(u);
}

// ---- prep: bf16-round all weight arrays into d_ws (flat f32) -------------
__global__ void mote_prep(const float* __restrict__ r1, const float* __restrict__ b1,
                          const float* __restrict__ r2, const float* __restrict__ b2,
                          const float* __restrict__ f,  const float* __restrict__ sp,
                          const float* __restrict__ rk, const float* __restrict__ wv,
                          float* __restrict__ ws)
{
    int t = blockIdx.x * blockDim.x + threadIdx.x;
    float v;
    if      (t <   32) v = r1[t];
    else if (t <   64) v = b1[t - 32];
    else if (t <  192) v = r2[t - 64];
    else if (t <  196) v = b2[t - 192];
    else if (t < 1220) v = f [t - 196];
    else if (t < 1732) v = sp[t - 1220];
    else if (t < 2244) v = rk[t - 1732];
    else if (t < 2756) v = wv[t - 2244];
    else return;
    ws[t] = bf16r(v);
}

constexpr int LROW = 36;   // 32 payload + 4 pad f32

// ---- main: r17 structure + 2-class wave desync. Even waves process
//      experts F,S,R,W; odd waves R,W,F,S — one wave-uniform if/else with
//      two straight-line bodies (VGPR = max of paths, NOT r19's 16-body
//      explosion). Anti-phase halves mean ~half the waves compute while
//      half store -> the write pipe drains continuously instead of in
//      lockstep bursts. Per-expert numerics byte-identical to r17.
__global__ __launch_bounds__(256) void mote_main(
    const float* __restrict__ x_in, int B,
    const float* __restrict__ ws,
    float* __restrict__ out_emb, float* __restrict__ out_rw,
    float* __restrict__ out_mask)
{
    __shared__ float sl[4][64][LROW];   // per-wave private slabs

    const int tid  = threadIdx.x;
    const int wid  = tid >> 6;
    const int lane = tid & 63;
    const size_t blockbase = (size_t)blockIdx.x * 256;
    const int b = (int)blockbase + tid;
    const bool valid = b < B;

    const float* rw1 = ws;
    const float* rb1 = ws + 32;
    const float* rw2 = ws + 64;
    const float* rb2 = ws + 192;
    const float* wf  = ws + 196;
    const float* wsp = ws + 1220;
    const float* wrk = ws + 1732;
    const float* wwv = ws + 2244;

    const float xb = bf16r(valid ? x_in[b] : 0.0f);

    // ---------------- router MLP in f32 + rare f64 fallback ----------------
    float lv[E] = { rb2[0], rb2[1], rb2[2], rb2[3] };
#pragma unroll
    for (int j = 0; j < H; ++j) {
        const float h = fmaxf(fmaf(xb, rw1[j], rb1[j]), 0.0f);
        lv[0] = fmaf(h, rw2[j * E + 0], lv[0]);
        lv[1] = fmaf(h, rw2[j * E + 1], lv[1]);
        lv[2] = fmaf(h, rw2[j * E + 2], lv[2]);
        lv[3] = fmaf(h, rw2[j * E + 3], lv[3]);
    }
    int i1 = 0;
#pragma unroll
    for (int e = 1; e < E; ++e) if (lv[e] > lv[i1]) i1 = e;
    int i2 = (i1 == 0) ? 1 : 0;
#pragma unroll
    for (int e = 0; e < E; ++e) if (e != i1 && lv[e] > lv[i2]) i2 = e;

    float third = -3.4e38f;
#pragma unroll
    for (int e = 0; e < E; ++e)
        if (e != i1 && e != i2) third = fmaxf(third, lv[e]);
    const bool close =
        (lv[i2] - third) < 1e-3f * fmaxf(1.0f, fabsf(lv[i2]));

    if (__any((int)close)) {
        const double xd = (double)xb;
        double l0 = (double)rb2[0], l1 = (double)rb2[1];
        double l2 = (double)rb2[2], l3 = (double)rb2[3];
#pragma unroll
        for (int j = 0; j < H; ++j) {
            const double h = fmax(fma(xd, (double)rw1[j], (double)rb1[j]), 0.0);
            l0 = fma(h, (double)rw2[j * E + 0], l0);
            l1 = fma(h, (double)rw2[j * E + 1], l1);
            l2 = fma(h, (double)rw2[j * E + 2], l2);
            l3 = fma(h, (double)rw2[j * E + 3], l3);
        }
        double ld[E] = { l0, l1, l2, l3 };
        i1 = 0;
#pragma unroll
        for (int e = 1; e < E; ++e) if (ld[e] > ld[i1]) i1 = e;
        i2 = (i1 == 0) ? 1 : 0;
#pragma unroll
        for (int e = 0; e < E; ++e) if (e != i1 && ld[e] > ld[i2]) i2 = e;
#pragma unroll
        for (int e = 0; e < E; ++e) lv[e] = (float)ld[e];
    }

    const float mx = fmaxf(fmaxf(lv[0], lv[1]), fmaxf(lv[2], lv[3]));
    const float e0 = __expf(lv[0] - mx);
    const float e1 = __expf(lv[1] - mx);
    const float e2 = __expf(lv[2] - mx);
    const float e3 = __expf(lv[3] - mx);
    const float inv = 1.0f / (e0 + e1 + e2 + e3);
    float w[E] = { e0 * inv, e1 * inv, e2 * inv, e3 * inv };

    float dw[E] = {0.f, 0.f, 0.f, 0.f};
    float mk[E] = {0.f, 0.f, 0.f, 0.f};
    dw[i1] = w[i1]; dw[i2] = w[i2];
    mk[i1] = 1.0f;  mk[i2] = 1.0f;

    if (valid) {
        f32x4 vrw = { bf16r(w[0]), bf16r(w[1]), bf16r(w[2]), bf16r(w[3]) };
        __builtin_nontemporal_store(vrw,
            reinterpret_cast<f32x4*>(out_rw + (size_t)E * b));
        f32x4 vmk = { mk[0], mk[1], mk[2], mk[3] };
        __builtin_nontemporal_store(vmk,
            reinterpret_cast<f32x4*>(out_mask + (size_t)E * b));
    }

    float acc[D];
    float (*slab)[LROW] = sl[wid];
    const size_t wrowbase = blockbase + (size_t)wid * 64;
    const int r8 = lane >> 3;
    const int q  = lane & 7;

#define STAGE_STORE(EIDX, DWV)                                                  \
    do {                                                                        \
        _Pragma("unroll")                                                       \
        for (int c = 0; c < D / 4; ++c) {                                       \
            f32x4 pk = { bf16r(acc[4*c+0] * (DWV)), bf16r(acc[4*c+1] * (DWV)),  \
                         bf16r(acc[4*c+2] * (DWV)), bf16r(acc[4*c+3] * (DWV)) };\
            *reinterpret_cast<f32x4*>(&slab[lane][c * 4]) = pk;                 \
        }                                                                       \
        _Pragma("unroll")                                                       \
        for (int it = 0; it < 8; ++it) {                                        \
            const int row = it * 8 + r8;                                        \
            const f32x4 v =                                                     \
                *reinterpret_cast<const f32x4*>(&slab[row][q * 4]);             \
            if (wrowbase + row < (size_t)B)                                     \
                __builtin_nontemporal_store(v,                                  \
                    reinterpret_cast<f32x4*>(out_emb + (wrowbase + row) * (E * D) \
                                             + (EIDX) * D + q * 4));            \
        }                                                                       \
    } while (0)

    // expert bodies (byte-identical numerics to r17)
#define EXP_F                                                                   \
    do {                                                                        \
        float phi[2 * K];                                                       \
        float s1, c1;                                                           \
        sincosf(xb, &s1, &c1);                                                  \
        phi[0] = s1; phi[K] = c1;                                               \
        float sk = s1, ck = c1;                                                 \
        _Pragma("unroll")                                                       \
        for (int k = 1; k < K; ++k) {                                           \
            const float sn = fmaf(sk, c1,  ck * s1);                            \
            const float cn = fmaf(ck, c1, -sk * s1);                            \
            sk = sn; ck = cn;                                                   \
            phi[k]     = sk;                                                    \
            phi[K + k] = ck;                                                    \
        }                                                                       \
        _Pragma("unroll")                                                       \
        for (int d = 0; d < D; ++d) acc[d] = 0.0f;                              \
        _Pragma("unroll")                                                       \
        for (int k = 0; k < 2 * K; ++k) {                                       \
            const float p = phi[k];                                             \
            _Pragma("unroll")                                                   \
            for (int d = 0; d < D; ++d)                                         \
                acc[d] = fmaf(p, wf[k * D + d], acc[d]);                        \
        }                                                                       \
        STAGE_STORE(0, dw[0]);                                                  \
    } while (0)

#define EXP_S                                                                   \
    do {                                                                        \
        float phi[K];                                                           \
        _Pragma("unroll")                                                       \
        for (int k = 0; k < K; ++k) {                                           \
            const float knot = (float)(-2.0 + (double)k * (4.0 / 15.0));        \
            const float r = fmaxf(xb - knot, 0.0f);                             \
            phi[k] = r * r * r;                                                 \
        }                                                                       \
        _Pragma("unroll")                                                       \
        for (int d = 0; d < D; ++d) acc[d] = 0.0f;                              \
        _Pragma("unroll")                                                       \
        for (int k = 0; k < K; ++k) {                                           \
            const float p = phi[k];                                             \
            _Pragma("unroll")                                                   \
            for (int d = 0; d < D; ++d)                                         \
                acc[d] = fmaf(p, wsp[k * D + d], acc[d]);                       \
        }                                                                       \
        STAGE_STORE(1, dw[1]);                                                  \
    } while (0)

#define EXP_R                                                                   \
    do {                                                                        \
        float phi[K];                                                           \
        _Pragma("unroll")                                                       \
        for (int k = 0; k < K; ++k) {                                           \
            const float knot = (float)(-2.0 + (double)k * (4.0 / 15.0));        \
            const float t = xb - knot;                                          \
            phi[k] = __expf(-4.0f * t * t);                                     \
        }                                                                       \
        _Pragma("unroll")                                                       \
        for (int d = 0; d < D; ++d) acc[d] = 0.0f;                              \
        _Pragma("unroll")                                                       \
        for (int k = 0; k < K; ++k) {                                           \
            const float p = phi[k];                                             \
            _Pragma("unroll")                                                   \
            for (int d = 0; d < D; ++d)                                         \
                acc[d] = fmaf(p, wrk[k * D + d], acc[d]);                       \
        }                                                                       \
        STAGE_STORE(2, dw[2]);                                                  \
    } while (0)

#define EXP_W                                                                   \
    do {                                                                        \
        float phi[K];                                                           \
        _Pragma("unroll")                                                       \
        for (int k = 0; k < K; ++k) {                                           \
            const float knot = (float)(-2.0 + (double)k * (4.0 / 15.0));        \
            const float z  = (xb - knot) * 2.0f;                                \
            const float z2 = z * z;                                             \
            phi[k] = (1.0f - z2) * __expf(-0.5f * z2);                          \
        }                                                                       \
        _Pragma("unroll")                                                       \
        for (int d = 0; d < D; ++d) acc[d] = 0.0f;                              \
        _Pragma("unroll")                                                       \
        for (int k = 0; k < K; ++k) {                                           \
            const float p = phi[k];                                             \
            _Pragma("unroll")                                                   \
            for (int d = 0; d < D; ++d)                                         \
                acc[d] = fmaf(p, wwv[k * D + d], acc[d]);                       \
        }                                                                       \
        STAGE_STORE(3, dw[3]);                                                  \
    } while (0)

    // 2-class anti-phase: even waves F,S,R,W; odd waves R,W,F,S.
    if ((wid & 1) == 0) {
        EXP_F; EXP_S; EXP_R; EXP_W;
    } else {
        EXP_R; EXP_W; EXP_F; EXP_S;
    }

#undef EXP_F
#undef EXP_S
#undef EXP_R
#undef EXP_W
#undef STAGE_STORE
}

extern "C" void kernel_launch(void* const* d_in, const int* in_sizes, int n_in,
                              void* d_out, int out_size, void* d_ws, size_t ws_size,
                              hipStream_t stream)
{
    const int B = in_sizes[0];   // timestamp_input (B,1) f32
    const float* x   = (const float*)d_in[0];
    const float* rw1 = (const float*)d_in[1];
    const float* rb1 = (const float*)d_in[2];
    const float* rw2 = (const float*)d_in[3];
    const float* rb2 = (const float*)d_in[4];
    const float* wf  = (const float*)d_in[5];
    const float* wsp = (const float*)d_in[6];
    const float* wrk = (const float*)d_in[7];
    const float* wwv = (const float*)d_in[8];

    float* ws = (float*)d_ws;

    // tuple layout, flat f32 (bf16-grained values) in return order:
    //   final_embedding (B*128) | raw_weights (B*4) | mask (B*4 as 1.0/0.0)
    float* out      = (float*)d_out;
    float* out_emb  = out;
    float* out_rw   = out + (size_t)B * (E * D);
    float* out_mask = out_rw + (size_t)B * E;

    hipLaunchKernelGGL(mote_prep, dim3(11), dim3(256), 0, stream,
                       rw1, rb1, rw2, rb2, wf, wsp, wrk, wwv, ws);

    const int block = 256;
    const int grid  = (B + block - 1) / block;
    hipLaunchKernelGGL(mote_main, dim3(grid), dim3(block), 0, stream,
                       x, B, ws, out_emb, out_rw, out_mask);
}